// Round 28
// baseline (89.651 us; speedup 1.0000x reference)
//
#include <hip/hip_runtime.h>
#include <stdint.h>

#define T_SEQ 2048
#define CEMB  1024
#define NHEAD 16
#define HS    64
#define NBH   32     // B*H
#define MROWS 4096   // B*T

typedef unsigned short u16;
typedef __attribute__((ext_vector_type(8)))  __bf16 bf16x8;
typedef __attribute__((ext_vector_type(4)))  float  f32x4;
typedef __attribute__((ext_vector_type(16))) float  f32x16;
typedef __attribute__((ext_vector_type(2)))  unsigned u32x2;

__device__ __forceinline__ u16 f2bf(float f) {
  union { float f; uint32_t u; } c; c.f = f;
  return (u16)((c.u + 0x7FFFu + ((c.u >> 16) & 1u)) >> 16);
}

// pack two f32 -> u32 of 2 bf16 (a in low half) via v_cvt_pk_bf16_f32
__device__ __forceinline__ uint32_t cvtpk(float a, float b) {
  uint32_t r;
  asm("v_cvt_pk_bf16_f32 %0, %1, %2" : "=v"(r) : "v"(a), "v"(b));
  return r;
}

// v_permlane32_swap_b32 via builtin (SSA-clean)
__device__ __forceinline__ void plswapu(uint32_t& a, uint32_t& b) {
  u32x2 r = __builtin_amdgcn_permlane32_swap(a, b, false, false);
  a = r[0]; b = r[1];
}
__device__ __forceinline__ float xhalf_max(float x) {
  uint32_t a = __float_as_uint(x), b = a;
  plswapu(a, b);
  return fmaxf(__uint_as_float(a), __uint_as_float(b));
}
__device__ __forceinline__ float xhalf_sum(float x) {
  uint32_t a = __float_as_uint(x), b = a;
  plswapu(a, b);
  return __uint_as_float(a) + __uint_as_float(b);
}

#define EXP2 __builtin_amdgcn_exp2f

__device__ __forceinline__ bf16x8 ld8(const u16* p) {
  return *(const bf16x8*)(const void*)p;
}

#define ASYNC_CP16(gsrc, ldst)                                                  \
  __builtin_amdgcn_global_load_lds(                                             \
      (const __attribute__((address_space(1))) void*)(gsrc),                    \
      (__attribute__((address_space(3))) void*)(ldst), 16, 0, 0)

// ---------------- convert x -> bf16 (8 elements/thread) ----------------
__global__ __launch_bounds__(256) void cvt_x_kernel(const float* __restrict__ x,
                                                    u16* __restrict__ xb) {
  size_t i = ((size_t)blockIdx.x * 256 + threadIdx.x) * 8;
  float4 v0 = *(const float4*)(x + i);
  float4 v1 = *(const float4*)(x + i + 4);
  uint4 o;
  o.x = cvtpk(v0.x, v0.y);
  o.y = cvtpk(v0.z, v0.w);
  o.z = cvtpk(v1.x, v1.y);
  o.w = cvtpk(v1.z, v1.w);
  *(uint4*)(xb + i) = o;
}

// ------- convert W[h][c][d] -> Wt[w][n=h*64+d][c] bf16 (B^T layout) -------
__global__ __launch_bounds__(256) void cvt_w_kernel(const float* __restrict__ Wq,
                                                    const float* __restrict__ Wk,
                                                    const float* __restrict__ Wv,
                                                    u16* __restrict__ Wt) {
  __shared__ float tile[64][65];
  int w = blockIdx.z, h = blockIdx.y;
  int c0 = blockIdx.x * 64;
  const float* W = ((w == 0) ? Wq : (w == 1) ? Wk : Wv) + (size_t)h * CEMB * HS;
  int tid = threadIdx.x;
  int r = tid >> 4;
  int d4 = (tid & 15) * 4;
#pragma unroll
  for (int p = 0; p < 4; ++p) {
    int row = p * 16 + r;
    float4 v = *(const float4*)(W + (size_t)(c0 + row) * HS + d4);
    tile[row][d4] = v.x; tile[row][d4 + 1] = v.y;
    tile[row][d4 + 2] = v.z; tile[row][d4 + 3] = v.w;
  }
  __syncthreads();
  u16* dst = Wt + ((size_t)w << 20);
#pragma unroll
  for (int p = 0; p < 4; ++p) {
    int d = p * 16 + r;
    ushort4 o;
    o.x = f2bf(tile[d4][d]);     o.y = f2bf(tile[d4 + 1][d]);
    o.z = f2bf(tile[d4 + 2][d]); o.w = f2bf(tile[d4 + 3][d]);
    *(ushort4*)(dst + (size_t)(h * 64 + d) * CEMB + c0 + d4) = o;
  }
}

// ---------------- projection GEMM: [4096x1024] x [1024x1024]^T ----------------
// z==2 (V) writes the TRANSPOSED layout Vt[bh][d][t] directly (ushort4 over t).
#define BM 128
#define BN 128
#define BK 64

__global__ __launch_bounds__(256, 3) void proj_gemm(const u16* __restrict__ xb,
                                                    const u16* __restrict__ Wt,
                                                    u16* __restrict__ Qb,
                                                    u16* __restrict__ Kb,
                                                    u16* __restrict__ Vt) {
  __shared__ u16 As[BM * BK];
  __shared__ u16 Bs[BN * BK];
  int z = blockIdx.z;
  const u16* Wz = Wt + (size_t)z * (1024 * 1024);
  int tile_m = blockIdx.x * BM;
  int tile_n = blockIdx.y * BN;
  int tid  = threadIdx.x;
  int lane = tid & 63;
  int wave = tid >> 6;
  int wr = wave >> 1, wc = wave & 1;
  int l15 = lane & 15, lg = lane >> 4;

  f32x4 acc[4][4] = {};

  for (int k0 = 0; k0 < CEMB; k0 += BK) {
#pragma unroll
    for (int j = 0; j < 4; ++j) {
      int off = j * 4096 + tid * 16;
      int row = off >> 7;
      int g   = (off >> 4) & 7;
      int col = ((g ^ (row & 7)) << 3);
      const u16* srcA = xb + (size_t)(tile_m + row) * CEMB + k0 + col;
      ASYNC_CP16(srcA, (char*)As + j * 4096 + wave * 1024);
      const u16* srcB = Wz + (size_t)(tile_n + row) * CEMB + k0 + col;
      ASYNC_CP16(srcB, (char*)Bs + j * 4096 + wave * 1024);
    }
    __syncthreads();

    bf16x8 af[2][4], bfr[2][4];
#pragma unroll
    for (int kk = 0; kk < 2; ++kk) {
#pragma unroll
      for (int m = 0; m < 4; ++m) {
        int row = wr * 64 + m * 16 + l15;
        int g   = kk * 4 + lg;
        af[kk][m] = *(const bf16x8*)(const void*)((const char*)As + row * 128 +
                                                  ((g ^ (row & 7)) << 4));
      }
#pragma unroll
      for (int n = 0; n < 4; ++n) {
        int row = wc * 64 + n * 16 + l15;
        int g   = kk * 4 + lg;
        bfr[kk][n] = *(const bf16x8*)(const void*)((const char*)Bs + row * 128 +
                                                   ((g ^ (row & 7)) << 4));
      }
    }
#pragma unroll
    for (int kk = 0; kk < 2; ++kk)
#pragma unroll
      for (int m = 0; m < 4; ++m)
#pragma unroll
        for (int n = 0; n < 4; ++n)
          acc[m][n] = __builtin_amdgcn_mfma_f32_16x16x32_bf16(af[kk][m], bfr[kk][n],
                                                              acc[m][n], 0, 0, 0);
    __syncthreads();
  }

  if (z == 2) {
#pragma unroll
    for (int m = 0; m < 4; ++m)
#pragma unroll
      for (int n = 0; n < 4; ++n) {
        int row0 = tile_m + wr * 64 + m * 16 + lg * 4;     // b*T + t0 (t0 % 4 == 0)
        int col  = tile_n + wc * 64 + n * 16 + l15;        // h*64 + d
        int b = row0 >> 11, t0 = row0 & 2047;
        int h = col >> 6,  d = col & 63;
        ushort4 o;
        o.x = f2bf(acc[m][n][0]); o.y = f2bf(acc[m][n][1]);
        o.z = f2bf(acc[m][n][2]); o.w = f2bf(acc[m][n][3]);
        *(ushort4*)(Vt + ((size_t)((b << 4) + h) * HS + d) * T_SEQ + t0) = o;
      }
  } else {
    u16* outp = (z == 0) ? Qb : Kb;
#pragma unroll
    for (int m = 0; m < 4; ++m)
#pragma unroll
      for (int n = 0; n < 4; ++n)
#pragma unroll
        for (int i = 0; i < 4; ++i) {
          int row = tile_m + wr * 64 + m * 16 + lg * 4 + i;  // b*T + t
          int col = tile_n + wc * 64 + n * 16 + l15;         // h*64 + d
          int b = row >> 11, t = row & 2047;
          int h = col >> 6,  d = col & 63;
          outp[(size_t)((b << 4) + h) * (T_SEQ * HS) + (size_t)t * HS + d] =
              f2bf(acc[m][n][i]);
        }
  }
}

// ---------------- causal flash attention v10 (round-10/17 proven) -----------
// 2-wave blocks, one 64-row q-tile (i = 31 - blockIdx.y, longest first):
//  (1) 4 LDS buffers, TWO tile-bodies per barrier period -> half the
//      barrier+vmcnt-drain events; softmax(t) can overlap S-MFMA(t+1).
//  (2) all cross-half exchanges via v_permlane32_swap_b32 builtin (VALU).
__global__ __launch_bounds__(128) void attn_kernel(const u16* __restrict__ Qb,
                                                   const u16* __restrict__ Kb,
                                                   const u16* __restrict__ Vt,
                                                   float* __restrict__ out) {
  __shared__ u16 Ks[4][4096];   // 4 x [64 kv][64 d]  (8 KB each, XOR-swizzled)
  __shared__ u16 Vs[4][4096];   // 4 x [64 d][64 kv]

  int bh = blockIdx.x;
  int i  = 31 - (int)blockIdx.y;   // q-tile index, longest first
  int tid = threadIdx.x;
  int lane = tid & 63, wave = tid >> 6;   // wave in {0,1}
  int l31 = lane & 31, hi = lane >> 5;
  int qw = i * 64 + wave * 32;

  const u16* Qh = Qb + (size_t)bh * T_SEQ * HS;
  const u16* Kh = Kb + (size_t)bh * T_SEQ * HS;
  const u16* Vh = Vt + (size_t)bh * HS * T_SEQ;

#define STAGE(tt, bb) do {                                                      \
    _Pragma("unroll")                                                           \
    for (int is = 0; is < 4; ++is) {                                            \
      int off_ = is * 2048 + tid * 16;                                          \
      int row_ = off_ >> 7;                                                     \
      int col_ = ((((off_ >> 4) & 7) ^ (row_ & 7)) << 3);                       \
      ASYNC_CP16(Kh + (size_t)((tt) * 64 + row_) * HS + col_,                   \
                 (char*)&Ks[bb][0] + is * 2048 + wave * 1024);                  \
      ASYNC_CP16(Vh + (size_t)row_ * T_SEQ + (tt) * 64 + col_,                  \
                 (char*)&Vs[bb][0] + is * 2048 + wave * 1024);                  \
    }                                                                           \
  } while (0)

  // Q B-frags: lane holds Q[qw+l31][kk*16 + hi*8 .. +8)
  bf16x8 qf[4];
#pragma unroll
  for (int kk = 0; kk < 4; ++kk)
    qf[kk] = ld8(Qh + (size_t)(qw + l31) * HS + kk * 16 + hi * 8);

  f32x16 ot0 = {}, ot1 = {};          // O^T: d 0..31 / 32..63
  float mrow = -1e30f, lsum = 0.f;
  const float sc = 0.03125f * 1.44269504f;   // log2(e)/sqrt(C)
  int lastt = i;

#define BODY(tt, bb) do {                                                       \
    bf16x8 kf[4][2];                                                            \
    _Pragma("unroll")                                                           \
    for (int kk = 0; kk < 4; ++kk) {                                            \
      int g = 2 * kk + hi;                                                      \
      int sw = ((g ^ (l31 & 7)) << 4);                                          \
      kf[kk][0] = *(const bf16x8*)(const void*)((const char*)&Ks[bb][0] +       \
                                                l31 * 128 + sw);                \
      kf[kk][1] = *(const bf16x8*)(const void*)((const char*)&Ks[bb][0] +       \
                                                (32 + l31) * 128 + sw);         \
    }                                                                           \
    f32x16 st0 = {}, st1 = {};                                                  \
    _Pragma("unroll")                                                           \
    for (int kk = 0; kk < 4; ++kk) {                                            \
      st0 = __builtin_amdgcn_mfma_f32_32x32x16_bf16(kf[kk][0], qf[kk], st0, 0, 0, 0); \
      st1 = __builtin_amdgcn_mfma_f32_32x32x16_bf16(kf[kk][1], qf[kk], st1, 0, 0, 0); \
    }                                                                           \
    if ((tt) == lastt) {                                                        \
      int qrel = qw + l31 - (tt) * 64 - 4 * hi;                                 \
      _Pragma("unroll")                                                         \
      for (int r = 0; r < 16; ++r) {                                            \
        int kr = (r & 3) + 8 * (r >> 2);                                        \
        if (kr > qrel)      st0[r] = -1e30f;                                    \
        if (kr + 32 > qrel) st1[r] = -1e30f;                                    \
      }                                                                         \
    }                                                                           \
    float pm0 = -1e30f, pm1 = -1e30f, pm2 = -1e30f, pm3 = -1e30f;               \
    _Pragma("unroll")                                                           \
    for (int r = 0; r < 16; r += 4) {                                           \
      pm0 = fmaxf(pm0, fmaxf(st0[r],     st1[r]));                              \
      pm1 = fmaxf(pm1, fmaxf(st0[r + 1], st1[r + 1]));                          \
      pm2 = fmaxf(pm2, fmaxf(st0[r + 2], st1[r + 2]));                          \
      pm3 = fmaxf(pm3, fmaxf(st0[r + 3], st1[r + 3]));                          \
    }                                                                           \
    float vmax = xhalf_max(fmaxf(fmaxf(pm0, pm1), fmaxf(pm2, pm3)));            \
    float vmaxL = vmax * sc;                                                    \
    if (!__all(vmaxL <= mrow + 8.0f)) {                                         \
      float mnew = fmaxf(mrow, vmaxL);                                          \
      float ps = EXP2(mrow - mnew);                                             \
      mrow = mnew;                                                              \
      lsum *= ps;                                                               \
      _Pragma("unroll")                                                         \
      for (int r = 0; r < 16; ++r) { ot0[r] *= ps; ot1[r] *= ps; }              \
    }                                                                           \
    float nm = -mrow;                                                           \
    float s0 = 0.f, s1 = 0.f, s2 = 0.f, s3 = 0.f;                               \
    _Pragma("unroll")                                                           \
    for (int r = 0; r < 16; r += 4) {                                           \
      st0[r]     = EXP2(fmaf(st0[r],     sc, nm));                              \
      st1[r]     = EXP2(fmaf(st1[r],     sc, nm));                              \
      st0[r + 1] = EXP2(fmaf(st0[r + 1], sc, nm));                              \
      st1[r + 1] = EXP2(fmaf(st1[r + 1], sc, nm));                              \
      st0[r + 2] = EXP2(fmaf(st0[r + 2], sc, nm));                              \
      st1[r + 2] = EXP2(fmaf(st1[r + 2], sc, nm));                              \
      st0[r + 3] = EXP2(fmaf(st0[r + 3], sc, nm));                              \
      st1[r + 3] = EXP2(fmaf(st1[r + 3], sc, nm));                              \
      s0 += st0[r]     + st1[r];                                                \
      s1 += st0[r + 1] + st1[r + 1];                                            \
      s2 += st0[r + 2] + st1[r + 2];                                            \
      s3 += st0[r + 3] + st1[r + 3];                                            \
    }                                                                           \
    lsum += xhalf_sum((s0 + s1) + (s2 + s3));                                   \
    bf16x8 pf[4];                                                               \
    _Pragma("unroll")                                                           \
    for (int kk = 0; kk < 4; ++kk) {                                            \
      int c = kk & 1;                                                           \
      float e0, e1, e2, e3, e4, e5, e6, e7;                                     \
      if (kk < 2) {                                                             \
        e0 = st0[8*c+0]; e1 = st0[8*c+1]; e2 = st0[8*c+2]; e3 = st0[8*c+3];     \
        e4 = st0[8*c+4]; e5 = st0[8*c+5]; e6 = st0[8*c+6]; e7 = st0[8*c+7];     \
      } else {                                                                  \
        e0 = st1[8*c+0]; e1 = st1[8*c+1]; e2 = st1[8*c+2]; e3 = st1[8*c+3];     \
        e4 = st1[8*c+4]; e5 = st1[8*c+5]; e6 = st1[8*c+6]; e7 = st1[8*c+7];     \
      }                                                                         \
      uint32_t w0 = cvtpk(e0, e1), w1 = cvtpk(e2, e3);                          \
      uint32_t w2 = cvtpk(e4, e5), w3 = cvtpk(e6, e7);                          \
      plswapu(w0, w2);                                                          \
      plswapu(w1, w3);                                                          \
      union { uint32_t w[4]; bf16x8 v; } u;                                     \
      u.w[0] = w0; u.w[1] = w1; u.w[2] = w2; u.w[3] = w3;                       \
      pf[kk] = u.v;                                                             \
    }                                                                           \
    _Pragma("unroll")                                                           \
    for (int kk = 0; kk < 4; ++kk) {                                            \
      int g = 2 * kk + hi;                                                      \
      int sw = ((g ^ (l31 & 7)) << 4);                                          \
      bf16x8 vf0 = *(const bf16x8*)(const void*)((const char*)&Vs[bb][0] +      \
                                                 l31 * 128 + sw);               \
      bf16x8 vf1 = *(const bf16x8*)(const void*)((const char*)&Vs[bb][0] +      \
                                                 (32 + l31) * 128 + sw);        \
      ot0 = __builtin_amdgcn_mfma_f32_32x32x16_bf16(vf0, pf[kk], ot0, 0, 0, 0); \
      ot1 = __builtin_amdgcn_mfma_f32_32x32x16_bf16(vf1, pf[kk], ot1, 0, 0, 0); \
    }                                                                           \
  } while (0)

  STAGE(0, 0);
  if (lastt >= 1) STAGE(1, 1);
  __syncthreads();

  for (int t = 0; t <= lastt; t += 2) {
    if (t + 2 <= lastt) STAGE(t + 2, (t + 2) & 3);
    if (t + 3 <= lastt) STAGE(t + 3, (t + 3) & 3);
    BODY(t, t & 3);
    if (t + 1 <= lastt) BODY(t + 1, (t + 1) & 3);
    __syncthreads();
  }
#undef STAGE
#undef BODY

  // ---- epilogue: lane owns q-row qw+l31; d = (r&3)+8*(r>>2)+4*hi (+32) ----
  int bb = bh >> 4, hh = bh & 15;
  int qrow = qw + l31;
  float inv = 1.0f / lsum;
  float* op = out + ((size_t)bb * T_SEQ + qrow) * CEMB + hh * HS + 4 * hi;
#pragma unroll
  for (int rq = 0; rq < 4; ++rq) {
    f32x4 v0, v1;
#pragma unroll
    for (int i2 = 0; i2 < 4; ++i2) {
      v0[i2] = ot0[4 * rq + i2] * inv;
      v1[i2] = ot1[4 * rq + i2] * inv;
    }
    *(f32x4*)(void*)(op + 8 * rq)      = v0;
    *(f32x4*)(void*)(op + 32 + 8 * rq) = v1;
  }
}

extern "C" void kernel_launch(void* const* d_in, const int* in_sizes, int n_in,
                              void* d_out, int out_size, void* d_ws, size_t ws_size,
                              hipStream_t stream) {
  const float* x  = (const float*)d_in[0];
  const float* Wq = (const float*)d_in[1];
  const float* Wk = (const float*)d_in[2];
  const float* Wv = (const float*)d_in[3];
  float* out = (float*)d_out;
  char* ws = (char*)d_ws;

  u16* xb = (u16*)ws;                      // 8 MB  [4096][1024] bf16
  u16* Wt = (u16*)(ws + (8u << 20));       // 6 MB  [3][1024][1024] bf16
  u16* Qb = (u16*)(ws + (14u << 20));      // 8 MB  [bh][t][d] bf16
  u16* Kb = (u16*)(ws + (22u << 20));      // 8 MB
  u16* Vt = (u16*)(ws + (30u << 20));      // 8 MB  [bh][d][t] bf16 (written by proj_gemm)

  cvt_x_kernel<<<2048, 256, 0, stream>>>(x, xb);
  cvt_w_kernel<<<dim3(16, 16, 3), 256, 0, stream>>>(Wq, Wk, Wv, Wt);
  proj_gemm<<<dim3(32, 8, 3), 256, 0, stream>>>(xb, Wt, Qb, Kb, Vt);
  attn_kernel<<<dim3(32, 32), 128, 0, stream>>>(Qb, Kb, Vt, out);
}

// Round 29
// 89.310 us; speedup vs baseline: 1.0038x; 1.0038x over previous
//
#include <hip/hip_runtime.h>
#include <stdint.h>

#define T_SEQ 2048
#define CEMB  1024
#define NHEAD 16
#define HS    64
#define NBH   32     // B*H
#define MROWS 4096   // B*T

typedef unsigned short u16;
typedef __attribute__((ext_vector_type(8)))  __bf16 bf16x8;
typedef __attribute__((ext_vector_type(4)))  float  f32x4;
typedef __attribute__((ext_vector_type(16))) float  f32x16;
typedef __attribute__((ext_vector_type(2)))  unsigned u32x2;

__device__ __forceinline__ u16 f2bf(float f) {
  union { float f; uint32_t u; } c; c.f = f;
  return (u16)((c.u + 0x7FFFu + ((c.u >> 16) & 1u)) >> 16);
}

// pack two f32 -> u32 of 2 bf16 (a in low half) via v_cvt_pk_bf16_f32
__device__ __forceinline__ uint32_t cvtpk(float a, float b) {
  uint32_t r;
  asm("v_cvt_pk_bf16_f32 %0, %1, %2" : "=v"(r) : "v"(a), "v"(b));
  return r;
}

// v_permlane32_swap_b32 via builtin (SSA-clean)
__device__ __forceinline__ void plswapu(uint32_t& a, uint32_t& b) {
  u32x2 r = __builtin_amdgcn_permlane32_swap(a, b, false, false);
  a = r[0]; b = r[1];
}
__device__ __forceinline__ float xhalf_max(float x) {
  uint32_t a = __float_as_uint(x), b = a;
  plswapu(a, b);
  return fmaxf(__uint_as_float(a), __uint_as_float(b));
}
__device__ __forceinline__ float xhalf_sum(float x) {
  uint32_t a = __float_as_uint(x), b = a;
  plswapu(a, b);
  return __uint_as_float(a) + __uint_as_float(b);
}

#define EXP2 __builtin_amdgcn_exp2f

__device__ __forceinline__ bf16x8 ld8(const u16* p) {
  return *(const bf16x8*)(const void*)p;
}

#define ASYNC_CP16(gsrc, ldst)                                                  \
  __builtin_amdgcn_global_load_lds(                                             \
      (const __attribute__((address_space(1))) void*)(gsrc),                    \
      (__attribute__((address_space(3))) void*)(ldst), 16, 0, 0)

// ---------------- convert x -> bf16 (8 elements/thread) ----------------
__global__ __launch_bounds__(256) void cvt_x_kernel(const float* __restrict__ x,
                                                    u16* __restrict__ xb) {
  size_t i = ((size_t)blockIdx.x * 256 + threadIdx.x) * 8;
  float4 v0 = *(const float4*)(x + i);
  float4 v1 = *(const float4*)(x + i + 4);
  uint4 o;
  o.x = cvtpk(v0.x, v0.y);
  o.y = cvtpk(v0.z, v0.w);
  o.z = cvtpk(v1.x, v1.y);
  o.w = cvtpk(v1.z, v1.w);
  *(uint4*)(xb + i) = o;
}

// ------- convert W[h][c][d] -> Wt[w][n=h*64+d][c] bf16 (B^T layout) -------
__global__ __launch_bounds__(256) void cvt_w_kernel(const float* __restrict__ Wq,
                                                    const float* __restrict__ Wk,
                                                    const float* __restrict__ Wv,
                                                    u16* __restrict__ Wt) {
  __shared__ float tile[64][65];
  int w = blockIdx.z, h = blockIdx.y;
  int c0 = blockIdx.x * 64;
  const float* W = ((w == 0) ? Wq : (w == 1) ? Wk : Wv) + (size_t)h * CEMB * HS;
  int tid = threadIdx.x;
  int r = tid >> 4;
  int d4 = (tid & 15) * 4;
#pragma unroll
  for (int p = 0; p < 4; ++p) {
    int row = p * 16 + r;
    float4 v = *(const float4*)(W + (size_t)(c0 + row) * HS + d4);
    tile[row][d4] = v.x; tile[row][d4 + 1] = v.y;
    tile[row][d4 + 2] = v.z; tile[row][d4 + 3] = v.w;
  }
  __syncthreads();
  u16* dst = Wt + ((size_t)w << 20);
#pragma unroll
  for (int p = 0; p < 4; ++p) {
    int d = p * 16 + r;
    ushort4 o;
    o.x = f2bf(tile[d4][d]);     o.y = f2bf(tile[d4 + 1][d]);
    o.z = f2bf(tile[d4 + 2][d]); o.w = f2bf(tile[d4 + 3][d]);
    *(ushort4*)(dst + (size_t)(h * 64 + d) * CEMB + c0 + d4) = o;
  }
}

// ---------------- projection GEMM: [4096x1024] x [1024x1024]^T ----------------
// z==2 (V) writes the TRANSPOSED layout Vt[bh][d][t] directly (ushort4 over t).
#define BM 128
#define BN 128
#define BK 64

__global__ __launch_bounds__(256, 3) void proj_gemm(const u16* __restrict__ xb,
                                                    const u16* __restrict__ Wt,
                                                    u16* __restrict__ Qb,
                                                    u16* __restrict__ Kb,
                                                    u16* __restrict__ Vt) {
  __shared__ u16 As[BM * BK];
  __shared__ u16 Bs[BN * BK];
  int z = blockIdx.z;
  const u16* Wz = Wt + (size_t)z * (1024 * 1024);
  int tile_m = blockIdx.x * BM;
  int tile_n = blockIdx.y * BN;
  int tid  = threadIdx.x;
  int lane = tid & 63;
  int wave = tid >> 6;
  int wr = wave >> 1, wc = wave & 1;
  int l15 = lane & 15, lg = lane >> 4;

  f32x4 acc[4][4] = {};

  for (int k0 = 0; k0 < CEMB; k0 += BK) {
#pragma unroll
    for (int j = 0; j < 4; ++j) {
      int off = j * 4096 + tid * 16;
      int row = off >> 7;
      int g   = (off >> 4) & 7;
      int col = ((g ^ (row & 7)) << 3);
      const u16* srcA = xb + (size_t)(tile_m + row) * CEMB + k0 + col;
      ASYNC_CP16(srcA, (char*)As + j * 4096 + wave * 1024);
      const u16* srcB = Wz + (size_t)(tile_n + row) * CEMB + k0 + col;
      ASYNC_CP16(srcB, (char*)Bs + j * 4096 + wave * 1024);
    }
    __syncthreads();

    bf16x8 af[2][4], bfr[2][4];
#pragma unroll
    for (int kk = 0; kk < 2; ++kk) {
#pragma unroll
      for (int m = 0; m < 4; ++m) {
        int row = wr * 64 + m * 16 + l15;
        int g   = kk * 4 + lg;
        af[kk][m] = *(const bf16x8*)(const void*)((const char*)As + row * 128 +
                                                  ((g ^ (row & 7)) << 4));
      }
#pragma unroll
      for (int n = 0; n < 4; ++n) {
        int row = wc * 64 + n * 16 + l15;
        int g   = kk * 4 + lg;
        bfr[kk][n] = *(const bf16x8*)(const void*)((const char*)Bs + row * 128 +
                                                   ((g ^ (row & 7)) << 4));
      }
    }
#pragma unroll
    for (int kk = 0; kk < 2; ++kk)
#pragma unroll
      for (int m = 0; m < 4; ++m)
#pragma unroll
        for (int n = 0; n < 4; ++n)
          acc[m][n] = __builtin_amdgcn_mfma_f32_16x16x32_bf16(af[kk][m], bfr[kk][n],
                                                              acc[m][n], 0, 0, 0);
    __syncthreads();
  }

  if (z == 2) {
#pragma unroll
    for (int m = 0; m < 4; ++m)
#pragma unroll
      for (int n = 0; n < 4; ++n) {
        int row0 = tile_m + wr * 64 + m * 16 + lg * 4;     // b*T + t0 (t0 % 4 == 0)
        int col  = tile_n + wc * 64 + n * 16 + l15;        // h*64 + d
        int b = row0 >> 11, t0 = row0 & 2047;
        int h = col >> 6,  d = col & 63;
        ushort4 o;
        o.x = f2bf(acc[m][n][0]); o.y = f2bf(acc[m][n][1]);
        o.z = f2bf(acc[m][n][2]); o.w = f2bf(acc[m][n][3]);
        *(ushort4*)(Vt + ((size_t)((b << 4) + h) * HS + d) * T_SEQ + t0) = o;
      }
  } else {
    u16* outp = (z == 0) ? Qb : Kb;
#pragma unroll
    for (int m = 0; m < 4; ++m)
#pragma unroll
      for (int n = 0; n < 4; ++n)
#pragma unroll
        for (int i = 0; i < 4; ++i) {
          int row = tile_m + wr * 64 + m * 16 + lg * 4 + i;  // b*T + t
          int col = tile_n + wc * 64 + n * 16 + l15;         // h*64 + d
          int b = row >> 11, t = row & 2047;
          int h = col >> 6,  d = col & 63;
          outp[(size_t)((b << 4) + h) * (T_SEQ * HS) + (size_t)t * HS + d] =
              f2bf(acc[m][n][i]);
        }
  }
}

// ---------------- causal flash attention v10 (round-10/17 proven) -----------
// 2-wave blocks, one 64-row q-tile (i = 31 - blockIdx.y, longest first):
//  (1) 4 LDS buffers, TWO tile-bodies per barrier period -> half the
//      barrier+vmcnt-drain events; softmax(t) can overlap S-MFMA(t+1).
//  (2) all cross-half exchanges via v_permlane32_swap_b32 builtin (VALU).
__global__ __launch_bounds__(128) void attn_kernel(const u16* __restrict__ Qb,
                                                   const u16* __restrict__ Kb,
                                                   const u16* __restrict__ Vt,
                                                   float* __restrict__ out) {
  __shared__ u16 Ks[4][4096];   // 4 x [64 kv][64 d]  (8 KB each, XOR-swizzled)
  __shared__ u16 Vs[4][4096];   // 4 x [64 d][64 kv]

  int bh = blockIdx.x;
  int i  = 31 - (int)blockIdx.y;   // q-tile index, longest first
  int tid = threadIdx.x;
  int lane = tid & 63, wave = tid >> 6;   // wave in {0,1}
  int l31 = lane & 31, hi = lane >> 5;
  int qw = i * 64 + wave * 32;

  const u16* Qh = Qb + (size_t)bh * T_SEQ * HS;
  const u16* Kh = Kb + (size_t)bh * T_SEQ * HS;
  const u16* Vh = Vt + (size_t)bh * HS * T_SEQ;

#define STAGE(tt, bb) do {                                                      \
    _Pragma("unroll")                                                           \
    for (int is = 0; is < 4; ++is) {                                            \
      int off_ = is * 2048 + tid * 16;                                          \
      int row_ = off_ >> 7;                                                     \
      int col_ = ((((off_ >> 4) & 7) ^ (row_ & 7)) << 3);                       \
      ASYNC_CP16(Kh + (size_t)((tt) * 64 + row_) * HS + col_,                   \
                 (char*)&Ks[bb][0] + is * 2048 + wave * 1024);                  \
      ASYNC_CP16(Vh + (size_t)row_ * T_SEQ + (tt) * 64 + col_,                  \
                 (char*)&Vs[bb][0] + is * 2048 + wave * 1024);                  \
    }                                                                           \
  } while (0)

  // Q B-frags: lane holds Q[qw+l31][kk*16 + hi*8 .. +8)
  bf16x8 qf[4];
#pragma unroll
  for (int kk = 0; kk < 4; ++kk)
    qf[kk] = ld8(Qh + (size_t)(qw + l31) * HS + kk * 16 + hi * 8);

  f32x16 ot0 = {}, ot1 = {};          // O^T: d 0..31 / 32..63
  float mrow = -1e30f, lsum = 0.f;
  const float sc = 0.03125f * 1.44269504f;   // log2(e)/sqrt(C)
  int lastt = i;

#define BODY(tt, bb) do {                                                       \
    bf16x8 kf[4][2];                                                            \
    _Pragma("unroll")                                                           \
    for (int kk = 0; kk < 4; ++kk) {                                            \
      int g = 2 * kk + hi;                                                      \
      int sw = ((g ^ (l31 & 7)) << 4);                                          \
      kf[kk][0] = *(const bf16x8*)(const void*)((const char*)&Ks[bb][0] +       \
                                                l31 * 128 + sw);                \
      kf[kk][1] = *(const bf16x8*)(const void*)((const char*)&Ks[bb][0] +       \
                                                (32 + l31) * 128 + sw);         \
    }                                                                           \
    f32x16 st0 = {}, st1 = {};                                                  \
    _Pragma("unroll")                                                           \
    for (int kk = 0; kk < 4; ++kk) {                                            \
      st0 = __builtin_amdgcn_mfma_f32_32x32x16_bf16(kf[kk][0], qf[kk], st0, 0, 0, 0); \
      st1 = __builtin_amdgcn_mfma_f32_32x32x16_bf16(kf[kk][1], qf[kk], st1, 0, 0, 0); \
    }                                                                           \
    if ((tt) == lastt) {                                                        \
      int qrel = qw + l31 - (tt) * 64 - 4 * hi;                                 \
      _Pragma("unroll")                                                         \
      for (int r = 0; r < 16; ++r) {                                            \
        int kr = (r & 3) + 8 * (r >> 2);                                        \
        if (kr > qrel)      st0[r] = -1e30f;                                    \
        if (kr + 32 > qrel) st1[r] = -1e30f;                                    \
      }                                                                         \
    }                                                                           \
    float pm0 = -1e30f, pm1 = -1e30f, pm2 = -1e30f, pm3 = -1e30f;               \
    _Pragma("unroll")                                                           \
    for (int r = 0; r < 16; r += 4) {                                           \
      pm0 = fmaxf(pm0, fmaxf(st0[r],     st1[r]));                              \
      pm1 = fmaxf(pm1, fmaxf(st0[r + 1], st1[r + 1]));                          \
      pm2 = fmaxf(pm2, fmaxf(st0[r + 2], st1[r + 2]));                          \
      pm3 = fmaxf(pm3, fmaxf(st0[r + 3], st1[r + 3]));                          \
    }                                                                           \
    float vmax = xhalf_max(fmaxf(fmaxf(pm0, pm1), fmaxf(pm2, pm3)));            \
    float vmaxL = vmax * sc;                                                    \
    if (!__all(vmaxL <= mrow + 8.0f)) {                                         \
      float mnew = fmaxf(mrow, vmaxL);                                          \
      float ps = EXP2(mrow - mnew);                                             \
      mrow = mnew;                                                              \
      lsum *= ps;                                                               \
      _Pragma("unroll")                                                         \
      for (int r = 0; r < 16; ++r) { ot0[r] *= ps; ot1[r] *= ps; }              \
    }                                                                           \
    float nm = -mrow;                                                           \
    float s0 = 0.f, s1 = 0.f, s2 = 0.f, s3 = 0.f;                               \
    _Pragma("unroll")                                                           \
    for (int r = 0; r < 16; r += 4) {                                           \
      st0[r]     = EXP2(fmaf(st0[r],     sc, nm));                              \
      st1[r]     = EXP2(fmaf(st1[r],     sc, nm));                              \
      st0[r + 1] = EXP2(fmaf(st0[r + 1], sc, nm));                              \
      st1[r + 1] = EXP2(fmaf(st1[r + 1], sc, nm));                              \
      st0[r + 2] = EXP2(fmaf(st0[r + 2], sc, nm));                              \
      st1[r + 2] = EXP2(fmaf(st1[r + 2], sc, nm));                              \
      st0[r + 3] = EXP2(fmaf(st0[r + 3], sc, nm));                              \
      st1[r + 3] = EXP2(fmaf(st1[r + 3], sc, nm));                              \
      s0 += st0[r]     + st1[r];                                                \
      s1 += st0[r + 1] + st1[r + 1];                                            \
      s2 += st0[r + 2] + st1[r + 2];                                            \
      s3 += st0[r + 3] + st1[r + 3];                                            \
    }                                                                           \
    lsum += xhalf_sum((s0 + s1) + (s2 + s3));                                   \
    bf16x8 pf[4];                                                               \
    _Pragma("unroll")                                                           \
    for (int kk = 0; kk < 4; ++kk) {                                            \
      int c = kk & 1;                                                           \
      float e0, e1, e2, e3, e4, e5, e6, e7;                                     \
      if (kk < 2) {                                                             \
        e0 = st0[8*c+0]; e1 = st0[8*c+1]; e2 = st0[8*c+2]; e3 = st0[8*c+3];     \
        e4 = st0[8*c+4]; e5 = st0[8*c+5]; e6 = st0[8*c+6]; e7 = st0[8*c+7];     \
      } else {                                                                  \
        e0 = st1[8*c+0]; e1 = st1[8*c+1]; e2 = st1[8*c+2]; e3 = st1[8*c+3];     \
        e4 = st1[8*c+4]; e5 = st1[8*c+5]; e6 = st1[8*c+6]; e7 = st1[8*c+7];     \
      }                                                                         \
      uint32_t w0 = cvtpk(e0, e1), w1 = cvtpk(e2, e3);                          \
      uint32_t w2 = cvtpk(e4, e5), w3 = cvtpk(e6, e7);                          \
      plswapu(w0, w2);                                                          \
      plswapu(w1, w3);                                                          \
      union { uint32_t w[4]; bf16x8 v; } u;                                     \
      u.w[0] = w0; u.w[1] = w1; u.w[2] = w2; u.w[3] = w3;                       \
      pf[kk] = u.v;                                                             \
    }                                                                           \
    _Pragma("unroll")                                                           \
    for (int kk = 0; kk < 4; ++kk) {                                            \
      int g = 2 * kk + hi;                                                      \
      int sw = ((g ^ (l31 & 7)) << 4);                                          \
      bf16x8 vf0 = *(const bf16x8*)(const void*)((const char*)&Vs[bb][0] +      \
                                                 l31 * 128 + sw);               \
      bf16x8 vf1 = *(const bf16x8*)(const void*)((const char*)&Vs[bb][0] +      \
                                                 (32 + l31) * 128 + sw);        \
      ot0 = __builtin_amdgcn_mfma_f32_32x32x16_bf16(vf0, pf[kk], ot0, 0, 0, 0); \
      ot1 = __builtin_amdgcn_mfma_f32_32x32x16_bf16(vf1, pf[kk], ot1, 0, 0, 0); \
    }                                                                           \
  } while (0)

  STAGE(0, 0);
  if (lastt >= 1) STAGE(1, 1);
  __syncthreads();

  for (int t = 0; t <= lastt; t += 2) {
    if (t + 2 <= lastt) STAGE(t + 2, (t + 2) & 3);
    if (t + 3 <= lastt) STAGE(t + 3, (t + 3) & 3);
    BODY(t, t & 3);
    if (t + 1 <= lastt) BODY(t + 1, (t + 1) & 3);
    __syncthreads();
  }
#undef STAGE
#undef BODY

  // ---- epilogue: lane owns q-row qw+l31; d = (r&3)+8*(r>>2)+4*hi (+32) ----
  int bb = bh >> 4, hh = bh & 15;
  int qrow = qw + l31;
  float inv = 1.0f / lsum;
  float* op = out + ((size_t)bb * T_SEQ + qrow) * CEMB + hh * HS + 4 * hi;
#pragma unroll
  for (int rq = 0; rq < 4; ++rq) {
    f32x4 v0, v1;
#pragma unroll
    for (int i2 = 0; i2 < 4; ++i2) {
      v0[i2] = ot0[4 * rq + i2] * inv;
      v1[i2] = ot1[4 * rq + i2] * inv;
    }
    *(f32x4*)(void*)(op + 8 * rq)      = v0;
    *(f32x4*)(void*)(op + 32 + 8 * rq) = v1;
  }
}

extern "C" void kernel_launch(void* const* d_in, const int* in_sizes, int n_in,
                              void* d_out, int out_size, void* d_ws, size_t ws_size,
                              hipStream_t stream) {
  const float* x  = (const float*)d_in[0];
  const float* Wq = (const float*)d_in[1];
  const float* Wk = (const float*)d_in[2];
  const float* Wv = (const float*)d_in[3];
  float* out = (float*)d_out;
  char* ws = (char*)d_ws;

  u16* xb = (u16*)ws;                      // 8 MB  [4096][1024] bf16
  u16* Wt = (u16*)(ws + (8u << 20));       // 6 MB  [3][1024][1024] bf16
  u16* Qb = (u16*)(ws + (14u << 20));      // 8 MB  [bh][t][d] bf16
  u16* Kb = (u16*)(ws + (22u << 20));      // 8 MB
  u16* Vt = (u16*)(ws + (30u << 20));      // 8 MB  [bh][d][t] bf16 (written by proj_gemm)

  cvt_x_kernel<<<2048, 256, 0, stream>>>(x, xb);
  cvt_w_kernel<<<dim3(16, 16, 3), 256, 0, stream>>>(Wq, Wk, Wv, Wt);
  proj_gemm<<<dim3(32, 8, 3), 256, 0, stream>>>(xb, Wt, Qb, Kb, Vt);
  attn_kernel<<<dim3(32, 32), 128, 0, stream>>>(Qb, Kb, Vt, out);
}